// Round 11
// baseline (116.873 us; speedup 1.0000x reference)
//
#include <hip/hip_runtime.h>
#include <math.h>

typedef __attribute__((ext_vector_type(8))) short  short8;    // 8 bf16 = 4 VGPRs
typedef __attribute__((ext_vector_type(4))) float  floatx4;   // MFMA C/D

#define MFMA16(a, b, c) __builtin_amdgcn_mfma_f32_16x16x32_bf16(a, b, c, 0, 0, 0)

constexpr int NSEQ = 2048;
constexpr int DIN  = 768;
constexpr int NH   = 12;
constexpr float QSCALE = 0.18033688011112042f;  // log2(e)/8

constexpr int PK = 72;   // 144 B rows, 16 B-aligned for b128

__device__ __forceinline__ ushort f2bf(float f) {   // RNE fp32 -> bf16
    unsigned u = __float_as_uint(f);
    u += 0x7FFF + ((u >> 16) & 1);
    return (ushort)(u >> 16);
}
__device__ __forceinline__ float bf2f(ushort u) {
    return __uint_as_float(((unsigned)u) << 16);
}
__device__ __forceinline__ unsigned cvt_pk_bf16(float lo, float hi) {
    unsigned r;
    asm("v_cvt_pk_bf16_f32 %0, %1, %2" : "=v"(r) : "v"(lo), "v"(hi));
    return r;
}
// pack 8 f32 -> 8 bf16 (RNE) with 4 instructions
__device__ __forceinline__ short8 pk8(float4 a, float4 b) {
    union { unsigned u[4]; short8 s; } r;
    r.u[0] = cvt_pk_bf16(a.x, a.y);
    r.u[1] = cvt_pk_bf16(a.z, a.w);
    r.u[2] = cvt_pk_bf16(b.x, b.y);
    r.u[3] = cvt_pk_bf16(b.z, b.w);
    return r.s;
}
// LDS-only barrier: orders ds ops across the block WITHOUT draining vmcnt,
// so register-prefetch global loads stay in flight across the barrier.
__device__ __forceinline__ void bar_lds() {
    asm volatile("s_waitcnt lgkmcnt(0)" ::: "memory");
    __builtin_amdgcn_s_barrier();
}

// -----------------------------------------------------------------------------
// Kernel 1: h = x @ Wq^T, fused f32->bf16, DOUBLE-BUFFERED LDS (r10 verified).
// BM=64 x BN=64, grid (64,12) = 768 blocks, 3/CU. UNCHANGED this round.
// -----------------------------------------------------------------------------
__global__ __launch_bounds__(256, 3)
void qkv_mfma(const float* __restrict__ x, const float* __restrict__ Wq,
              ushort* __restrict__ h)
{
    __shared__ ushort As[2][64 * PK];    // [buf][row][k]
    __shared__ ushort Bs[2][64 * PK];    // [buf][col][k]

    const int tid  = threadIdx.x;
    const int w    = tid >> 6;
    const int lane = tid & 63;
    const int m    = lane & 15;
    const int quad = lane >> 4;
    const int r0   = blockIdx.x * 64;
    const int c0   = blockIdx.y * 64;
    const int mrow0 = (w & 1) * 32;
    const int ncol0 = (w >> 1) * 32;

    const int srow = tid >> 3;          // staging row 0..31 (+32 for i=1)
    const int scol = (tid & 7) * 8;     // staging col (8 floats)

    floatx4 C[2][2] = {};
    float4 arf[2][2], brf[2][2];        // f32 prefetch regs (8 floats per i)

    #pragma unroll
    for (int i = 0; i < 2; ++i) {
        const float* ax = x  + (size_t)(r0 + srow + i * 32) * DIN + scol;
        const float* bx = Wq + (size_t)(c0 + srow + i * 32) * DIN + scol;
        arf[i][0] = ((const float4*)ax)[0]; arf[i][1] = ((const float4*)ax)[1];
        brf[i][0] = ((const float4*)bx)[0]; brf[i][1] = ((const float4*)bx)[1];
    }
    #pragma unroll
    for (int i = 0; i < 2; ++i) {
        *(short8*)&As[0][(srow + i * 32) * PK + scol] = pk8(arf[i][0], arf[i][1]);
        *(short8*)&Bs[0][(srow + i * 32) * PK + scol] = pk8(brf[i][0], brf[i][1]);
    }
    #pragma unroll
    for (int i = 0; i < 2; ++i) {
        const float* ax = x  + (size_t)(r0 + srow + i * 32) * DIN + 64 + scol;
        const float* bx = Wq + (size_t)(c0 + srow + i * 32) * DIN + 64 + scol;
        arf[i][0] = ((const float4*)ax)[0]; arf[i][1] = ((const float4*)ax)[1];
        brf[i][0] = ((const float4*)bx)[0]; brf[i][1] = ((const float4*)bx)[1];
    }
    bar_lds();

    for (int kk = 0; kk < 12; ++kk) {
        const int cur = kk & 1;

        #pragma unroll
        for (int kt2 = 0; kt2 < 2; ++kt2) {
            short8 a0 = *(const short8*)&As[cur][(mrow0 + m)      * PK + kt2 * 32 + quad * 8];
            short8 a1 = *(const short8*)&As[cur][(mrow0 + 16 + m) * PK + kt2 * 32 + quad * 8];
            short8 b0 = *(const short8*)&Bs[cur][(ncol0 + m)      * PK + kt2 * 32 + quad * 8];
            short8 b1 = *(const short8*)&Bs[cur][(ncol0 + 16 + m) * PK + kt2 * 32 + quad * 8];
            C[0][0] = MFMA16(a0, b0, C[0][0]);
            C[0][1] = MFMA16(a0, b1, C[0][1]);
            C[1][0] = MFMA16(a1, b0, C[1][0]);
            C[1][1] = MFMA16(a1, b1, C[1][1]);
        }

        if (kk + 1 < 12) {
            const int nxt = cur ^ 1;
            #pragma unroll
            for (int i = 0; i < 2; ++i) {
                *(short8*)&As[nxt][(srow + i * 32) * PK + scol] = pk8(arf[i][0], arf[i][1]);
                *(short8*)&Bs[nxt][(srow + i * 32) * PK + scol] = pk8(brf[i][0], brf[i][1]);
            }
            if (kk + 2 < 12) {
                const int k0 = (kk + 2) * 64;
                #pragma unroll
                for (int i = 0; i < 2; ++i) {
                    const float* ax = x  + (size_t)(r0 + srow + i * 32) * DIN + k0 + scol;
                    const float* bx = Wq + (size_t)(c0 + srow + i * 32) * DIN + k0 + scol;
                    arf[i][0] = ((const float4*)ax)[0]; arf[i][1] = ((const float4*)ax)[1];
                    brf[i][0] = ((const float4*)bx)[0]; brf[i][1] = ((const float4*)bx)[1];
                }
            }
            bar_lds();                  // ONE barrier per iteration
        }
    }

    #pragma unroll
    for (int mt = 0; mt < 2; ++mt)
        #pragma unroll
        for (int nt = 0; nt < 2; ++nt) {
            int cg = c0 + ncol0 + nt * 16 + m;
            int head = cg >> 6, d = cg & 63;
            #pragma unroll
            for (int r = 0; r < 4; ++r) {
                int rg = r0 + mrow0 + mt * 16 + quad * 4 + r;
                int b = rg >> 11, q = rg & 2047;
                h[((size_t)(b * NH + head) * NSEQ + q) * 64 + d] = f2bf(C[mt][nt][r]);
            }
        }
}

// -----------------------------------------------------------------------------
// Kernel 2: causal flash attention — 4-wave SINGLE-QT blocks, 6-7 blocks/CU.
// Combines the two measured wins: r9's 4-wave qsub x khalf split (short chain)
// + r1's 1536-block alternation-balanced grid. Single-buffered Ks/Vt/Ps =
// 23 KB -> 6-7 blocks/CU = 24-28 waves (2x r9/r10's TLP; occupancy was the
// binding constraint: 23% measured, no pipe >37%). 2 bar_lds per iteration
// (price of single-buffer); register prefetch 1 tile ahead stays in flight
// across both barriers. qt = alt(bh) ? xi : 63-xi gives each CU 3
// complementary pairs ~ 99 iters -> flat finish. No setprio.
// -----------------------------------------------------------------------------
__global__ __launch_bounds__(256, 6)
void attn_mfma(const ushort* __restrict__ h, float* __restrict__ out)
{
    __shared__ ushort Ks[64 * PK];      // [key][d]
    __shared__ ushort Vt[64 * PK];      // [d][key]
    __shared__ ushort Ps[2 * 16 * PK];  // [qsub][q][key]

    const int tid  = threadIdx.x;
    const int w    = tid >> 6;          // 0..3
    const int lane = tid & 63;
    const int m    = lane & 15;
    const int quad = lane >> 4;
    const int qsub = w & 1;             // q-subtile 0/1 (16 q each)
    const int khalf= w >> 1;            // key-half 0/1 (32 keys each)

    const int xi = blockIdx.x;          // 0..63
    const int bh = blockIdx.y;          // 0..23
    const int qt = ((bh >> 2) & 1) ? xi : (63 - xi);   // balanced per CU
    const int q0 = qt * 32;
    const int wq = q0 + qsub * 16;      // this wave's q base
    const int nkt = (qt >> 1) + 1;      // # of 64-key tiles
    const ushort* __restrict__ Hh = h + (size_t)bh * NSEQ * 64;
    ushort* Psw = Ps + qsub * 16 * PK;

    const int kr2  = (tid & 31) * 2;    // staging: 2 adjacent key rows
    const int part = tid >> 5;          // d-chunk 0..7 (8 d each)
    const int db   = part * 8;

    // Q fragments (B-operand: n=q=m, k=d), pre-scaled by log2(e)/8
    short8 qa[2];
    #pragma unroll
    for (int kt2 = 0; kt2 < 2; ++kt2) {
        short8 raw = *(const short8*)(Hh + (size_t)(wq + m) * 64 + kt2 * 32 + quad * 8);
        #pragma unroll
        for (int j = 0; j < 8; ++j)
            qa[kt2][j] = (short)f2bf(bf2f((ushort)raw[j]) * QSCALE);
    }

    floatx4 O[4] = {};                  // O^T partial (khalf keys): d=mt*16+quad*4+r, q=m
    float lacc = 0.0f;

    short8 pre0, pre1;                  // prefetched K rows kr2, kr2+1 (8 d each)
    {
        const ushort* src = Hh + (size_t)kr2 * 64 + db;
        pre0 = *(const short8*)src;
        pre1 = *(const short8*)(src + 64);
    }

    for (int kt = 0; kt < nkt; ++kt) {
        bar_lds();                      // all waves' S/PV reads of prev tile done

        // ---- stage K tile + V^T (packed key-pairs per dword) ----
        *(short8*)&Ks[kr2       * PK + db] = pre0;
        *(short8*)&Ks[(kr2 + 1) * PK + db] = pre1;
        union { short8 v; ushort u[8]; } ua, ub;
        ua.v = pre0; ub.v = pre1;
        #pragma unroll
        for (int i = 0; i < 8; ++i)
            *(unsigned*)&Vt[(db + i) * PK + kr2] =
                (unsigned)ua.u[i] | ((unsigned)ub.u[i] << 16);
        if (kt + 1 < nkt) {             // prefetch next tile (in flight across bars)
            const ushort* src = Hh + (size_t)((kt + 1) * 64 + kr2) * 64 + db;
            pre0 = *(const short8*)src;
            pre1 = *(const short8*)(src + 64);
        }
        bar_lds();                      // staging visible to all waves

        // ---- S^T = K Q^T : this wave's 32 keys (khalf) x its 16 q ----
        floatx4 S[2] = {};
        #pragma unroll
        for (int kt2 = 0; kt2 < 2; ++kt2)
            #pragma unroll
            for (int mt2 = 0; mt2 < 2; ++mt2) {
                short8 ka = *(const short8*)
                    &Ks[(khalf * 32 + mt2 * 16 + m) * PK + kt2 * 32 + quad * 8];
                S[mt2] = MFMA16(ka, qa[kt2], S[mt2]);
            }

        // ---- exp2 + packed P write + l accumulate (own key-half) ----
        const int lim  = wq + m - kt * 64;
        const bool diag = (kt == nkt - 1);
        #pragma unroll
        for (int mt2 = 0; mt2 < 2; ++mt2) {
            const int kb = (khalf * 2 + mt2) * 16 + quad * 4;   // key-in-tile base
            float p0, p1, p2, p3;
            if (diag) {
                p0 = (kb + 0 <= lim) ? exp2f(S[mt2][0]) : 0.0f;
                p1 = (kb + 1 <= lim) ? exp2f(S[mt2][1]) : 0.0f;
                p2 = (kb + 2 <= lim) ? exp2f(S[mt2][2]) : 0.0f;
                p3 = (kb + 3 <= lim) ? exp2f(S[mt2][3]) : 0.0f;
            } else {
                p0 = exp2f(S[mt2][0]);
                p1 = exp2f(S[mt2][1]);
                p2 = exp2f(S[mt2][2]);
                p3 = exp2f(S[mt2][3]);
            }
            lacc += (p0 + p1) + (p2 + p3);
            uint2 pw;
            pw.x = cvt_pk_bf16(p0, p1);
            pw.y = cvt_pk_bf16(p2, p3);
            *(uint2*)&Psw[m * PK + kb] = pw;
        }

        // ---- O^T += V^T P^T over own 32 keys: 4 MFMAs (k=32) ----
        short8 pb = *(const short8*)&Psw[m * PK + khalf * 32 + quad * 8];
        #pragma unroll
        for (int mt = 0; mt < 4; ++mt) {
            short8 va = *(const short8*)
                &Vt[(mt * 16 + m) * PK + khalf * 32 + quad * 8];
            O[mt] = MFMA16(va, pb, O[mt]);
        }
    }

    // ---- merge key-half partials (Ks reused as scratch) ----
    lacc += __shfl_xor(lacc, 16);
    lacc += __shfl_xor(lacc, 32);

    float* Om = (float*)&Ks[0];         // [2][64][pitch 17] = 8704 B (fits 9216)
    float* Lm = Om + 2 * 64 * 17;       // [2][16]
    bar_lds();                          // all PV reads done; Ks free
    if (khalf == 1) {
        #pragma unroll
        for (int mt = 0; mt < 4; ++mt)
            #pragma unroll
            for (int r = 0; r < 4; ++r) {
                int d = mt * 16 + quad * 4 + r;
                Om[(qsub * 64 + d) * 17 + m] = O[mt][r];
            }
        if (quad == 0) Lm[qsub * 16 + m] = lacc;
    }
    bar_lds();
    if (khalf == 0) {
        float linv = 1.0f / (lacc + Lm[qsub * 16 + m]);
        #pragma unroll
        for (int mt = 0; mt < 4; ++mt)
            #pragma unroll
            for (int r = 0; r < 4; ++r) {
                int d = mt * 16 + quad * 4 + r;
                float v = O[mt][r] + Om[(qsub * 64 + d) * 17 + m];
                out[((size_t)bh * 64 + d) * NSEQ + q0 + qsub * 16 + m] = v * linv;
            }
    }
}

extern "C" void kernel_launch(void* const* d_in, const int* in_sizes, int n_in,
                              void* d_out, int out_size, void* d_ws, size_t ws_size,
                              hipStream_t stream)
{
    (void)in_sizes; (void)n_in; (void)out_size; (void)ws_size;
    const float* x  = (const float*)d_in[0];
    const float* Wq = (const float*)d_in[1];
    float* out = (float*)d_out;

    ushort* hb = (ushort*)d_ws;                 // 6.29 MB (ws is 256 MiB)

    qkv_mfma<<<dim3(64, 12), dim3(256), 0, stream>>>(x, Wq, hb);
    attn_mfma<<<dim3(64, 24), dim3(256), 0, stream>>>(hb, out);
}